// Round 13
// baseline (94.033 us; speedup 1.0000x reference)
//
#include <hip/hip_runtime.h>
#include <math.h>

#define BB 8
#define SS 4096
#define DD 1024
#define KK 3072
#define NCHUNK 8
#define CHUNK 512          // SS / NCHUNK candidates per block
#define NELEM (BB * SS)    // 32768

typedef unsigned long long u64;
typedef unsigned int u32;
typedef float f32x4 __attribute__((ext_vector_type(4)));

// ---------------- Kernel 1: scores + sortable keys --------------------------------
// One wave (64 lanes) per 2 token rows (w_router held in regs across both).
// key = (~mono(score) << 32) | index : ascending key == descending score,
// ties by lower index (lax.top_k stable order).
__global__ __launch_bounds__(256) void mod_scores(const float* __restrict__ x,
                                                  const float* __restrict__ w,
                                                  float* __restrict__ scores,
                                                  u64* __restrict__ keys) {
    int wave = (int)((blockIdx.x * blockDim.x + threadIdx.x) >> 6);
    int lane = threadIdx.x & 63;
    const float4* wr = (const float4*)w;
    float4 wl[4];
#pragma unroll
    for (int i = 0; i < 4; ++i) wl[i] = wr[lane + 64 * i];
#pragma unroll
    for (int rr = 0; rr < 2; ++rr) {
        int row = wave * 2 + rr;
        const float4* xr = (const float4*)(x + (size_t)row * DD);
        float acc = 0.f;
#pragma unroll
        for (int i = 0; i < 4; ++i) {
            float4 a = xr[lane + 64 * i];
            float4 b = wl[i];
            acc += a.x * b.x + a.y * b.y + a.z * b.z + a.w * b.w;
        }
#pragma unroll
        for (int off = 32; off > 0; off >>= 1)
            acc += __shfl_down(acc, off, 64);
        if (lane == 0) {
            scores[row] = acc;
            u32 u = __float_as_uint(acc);
            u32 m = (u & 0x80000000u) ? ~u : (u | 0x80000000u);  // monotonic ascending
            keys[row] = ((u64)(~m) << 32) | (u32)(row & (SS - 1));
        }
    }
}

// ---------------- Kernel 2: tiled partial rank (ballot-vectorized, round-5 proven) -
__global__ __launch_bounds__(256) void mod_rank_partial(const u64* __restrict__ keys,
                                                        int* __restrict__ pcnt) {
    __shared__ __align__(16) u64 lk[CHUNK];
    const int ob = blockIdx.x / NCHUNK;
    const int c  = blockIdx.x - ob * NCHUNK;
    const int tid = threadIdx.x;
    const int gid = ob * 256 + tid;
    const int b = gid >> 12;
    const int lane = tid & 63;

    const u64* __restrict__ cand = keys + ((size_t)b << 12) + c * CHUNK;
    *(ulonglong2*)&lk[tid * 2] = *(const ulonglong2*)&cand[tid * 2];
    __syncthreads();

    const u64 my = keys[gid];
    const u32 my_hi = (u32)(my >> 32);
    const u32 my_lo = (u32)my;

    int v_cnt = 0;   // lane i ends up holding owner-i's count
#pragma unroll
    for (int g = 0; g < 8; ++g) {
        u64 mj[8];
#pragma unroll
        for (int j = 0; j < 8; ++j) {
            u32 h = (u32)__builtin_amdgcn_readlane((int)my_hi, g * 8 + j);
            u32 l = (u32)__builtin_amdgcn_readlane((int)my_lo, g * 8 + j);
            mj[j] = ((u64)h << 32) | l;
        }
        int cnt[8] = {0, 0, 0, 0, 0, 0, 0, 0};
#pragma unroll
        for (int cg = 0; cg < CHUNK / 64; ++cg) {   // 8 iterations, unrolled
            u64 cv = lk[cg * 64 + lane];            // lane-strided: 64 cands / read
#pragma unroll
            for (int j = 0; j < 8; ++j)
                cnt[j] += (int)__popcll(__ballot(cv < mj[j]));  // 64 pairs / v_cmp
        }
#pragma unroll
        for (int j = 0; j < 8; ++j)                  // cnt[j] is wave-uniform
            v_cnt = (lane == g * 8 + j) ? cnt[j] : v_cnt;
    }
    pcnt[c * NELEM + gid] = v_cnt;
}

// ---------------- Kernel 3: finalize rank + partial softmax denominator -----------
__global__ __launch_bounds__(256) void mod_finalize(const int* __restrict__ pcnt,
                                                    const float* __restrict__ scores,
                                                    int* __restrict__ rank_of,
                                                    float* __restrict__ partial) {
    const int gid = blockIdx.x * 256 + threadIdx.x;
    int r = 0;
#pragma unroll
    for (int c = 0; c < NCHUNK; ++c) r += pcnt[c * NELEM + gid];
    rank_of[gid] = r;

    float e = (r < KK) ? expf(scores[gid]) : 0.f;
    __shared__ float red[256];
    red[threadIdx.x] = e;
    __syncthreads();
    for (int off = 128; off > 0; off >>= 1) {
        if (threadIdx.x < off) red[threadIdx.x] += red[threadIdx.x + off];
        __syncthreads();
    }
    if (threadIdx.x == 0) partial[blockIdx.x] = red[0];
}

// ---------------- Kernel 4: blend, 8 rows per block (4096 blocks) ------------------
// Denom hoisted (computed once per block); descending block order (r12-neutral
// but harmless); proc loads / out stores non-temporal.
__global__ __launch_bounds__(256) void mod_blend(const float* __restrict__ x,
                                                 const float* __restrict__ proc,
                                                 const int* __restrict__ rank_of,
                                                 const float* __restrict__ scores,
                                                 const float* __restrict__ partial,
                                                 float* __restrict__ out) {
    const int grp = (int)(gridDim.x - 1 - blockIdx.x);   // descending
    const int row0 = grp * 8;
    const int b = row0 >> 12;                            // 8 rows share a batch
    const int t = threadIdx.x;

    float denom = 0.f;
#pragma unroll
    for (int i = 0; i < 16; ++i) denom += partial[b * 16 + i];  // deterministic
    float rdenom = 1.f / denom;

#pragma unroll
    for (int r = 0; r < 8; ++r) {
        const int row = row0 + r;
        const f32x4* xr = (const f32x4*)(x + (size_t)row * DD);
        f32x4* orow = (f32x4*)(out + (size_t)row * DD);
        const int j = rank_of[row];       // uniform -> s_load
        f32x4 a = xr[t];
        if (j < KK) {
            float wgt = expf(scores[row]) * rdenom;
            const f32x4* pr = (const f32x4*)(proc + ((size_t)b * KK + j) * DD);
            f32x4 p = __builtin_nontemporal_load(pr + t);
            f32x4 o = p * wgt + (1.f - wgt) * a;
            __builtin_nontemporal_store(o, orow + t);
        } else {
            __builtin_nontemporal_store(a, orow + t);
        }
    }
}

extern "C" void kernel_launch(void* const* d_in, const int* in_sizes, int n_in,
                              void* d_out, int out_size, void* d_ws, size_t ws_size,
                              hipStream_t stream) {
    const float* x    = (const float*)d_in[0];   // (B,S,D)
    const float* proc = (const float*)d_in[1];   // (B,K,D)
    const float* w    = (const float*)d_in[2];   // (D,)
    float* out = (float*)d_out;

    // workspace layout
    u64*   keys    = (u64*)d_ws;                                   // 256 KB
    float* scores  = (float*)((char*)d_ws + NELEM * 8);            // 128 KB
    int*   rank_of = (int*)((char*)d_ws + NELEM * 12);             // 128 KB
    int*   pcnt    = (int*)((char*)d_ws + NELEM * 16);             // 1 MB
    float* partial = (float*)((char*)d_ws + NELEM * 16 + NELEM * 4 * NCHUNK); // 512 B

    mod_scores      <<<NELEM / 8, 256, 0, stream>>>(x, w, scores, keys);
    mod_rank_partial<<<(NELEM / 256) * NCHUNK, 256, 0, stream>>>(keys, pcnt);
    mod_finalize    <<<NELEM / 256, 256, 0, stream>>>(pcnt, scores, rank_of, partial);
    mod_blend       <<<NELEM / 8, 256, 0, stream>>>(x, proc, rank_of, scores, partial, out);
}

// Round 14
// 91.688 us; speedup vs baseline: 1.0256x; 1.0256x over previous
//
#include <hip/hip_runtime.h>
#include <math.h>

#define BB 8
#define SS 4096
#define DD 1024
#define KK 3072
#define NCHUNK 8
#define CHUNK 512          // SS / NCHUNK candidates per block
#define NELEM (BB * SS)    // 32768

typedef unsigned long long u64;
typedef unsigned int u32;
typedef float f32x4 __attribute__((ext_vector_type(4)));

// ---------------- Kernel 1: scores + sortable keys --------------------------------
// One wave (64 lanes) per token row. key = (~mono(score) << 32) | index :
// ascending key == descending score, ties by lower index (lax.top_k stable order).
__global__ __launch_bounds__(256) void mod_scores(const float* __restrict__ x,
                                                  const float* __restrict__ w,
                                                  float* __restrict__ scores,
                                                  u64* __restrict__ keys) {
    int wave = (int)((blockIdx.x * blockDim.x + threadIdx.x) >> 6);
    int lane = threadIdx.x & 63;
    if (wave >= NELEM) return;
    const float4* xr = (const float4*)(x + (size_t)wave * DD);
    const float4* wr = (const float4*)w;
    float acc = 0.f;
#pragma unroll
    for (int i = 0; i < 4; ++i) {
        float4 a = xr[lane + 64 * i];
        float4 b = wr[lane + 64 * i];
        acc += a.x * b.x + a.y * b.y + a.z * b.z + a.w * b.w;
    }
#pragma unroll
    for (int off = 32; off > 0; off >>= 1)
        acc += __shfl_down(acc, off, 64);
    if (lane == 0) {
        scores[wave] = acc;
        u32 u = __float_as_uint(acc);
        u32 m = (u & 0x80000000u) ? ~u : (u | 0x80000000u);  // monotonic ascending
        keys[wave] = ((u64)(~m) << 32) | (u32)(wave & (SS - 1));
    }
}

// ---------------- Kernel 2: tiled partial rank (ballot-vectorized, round-5 proven) -
__global__ __launch_bounds__(256) void mod_rank_partial(const u64* __restrict__ keys,
                                                        int* __restrict__ pcnt) {
    __shared__ __align__(16) u64 lk[CHUNK];
    const int ob = blockIdx.x / NCHUNK;
    const int c  = blockIdx.x - ob * NCHUNK;
    const int tid = threadIdx.x;
    const int gid = ob * 256 + tid;
    const int b = gid >> 12;
    const int lane = tid & 63;

    const u64* __restrict__ cand = keys + ((size_t)b << 12) + c * CHUNK;
    *(ulonglong2*)&lk[tid * 2] = *(const ulonglong2*)&cand[tid * 2];
    __syncthreads();

    const u64 my = keys[gid];
    const u32 my_hi = (u32)(my >> 32);
    const u32 my_lo = (u32)my;

    int v_cnt = 0;   // lane i ends up holding owner-i's count
#pragma unroll
    for (int g = 0; g < 8; ++g) {
        u64 mj[8];
#pragma unroll
        for (int j = 0; j < 8; ++j) {
            u32 h = (u32)__builtin_amdgcn_readlane((int)my_hi, g * 8 + j);
            u32 l = (u32)__builtin_amdgcn_readlane((int)my_lo, g * 8 + j);
            mj[j] = ((u64)h << 32) | l;
        }
        int cnt[8] = {0, 0, 0, 0, 0, 0, 0, 0};
#pragma unroll
        for (int cg = 0; cg < CHUNK / 64; ++cg) {   // 8 iterations, unrolled
            u64 cv = lk[cg * 64 + lane];            // lane-strided: 64 cands / read
#pragma unroll
            for (int j = 0; j < 8; ++j)
                cnt[j] += (int)__popcll(__ballot(cv < mj[j]));  // 64 pairs / v_cmp
        }
#pragma unroll
        for (int j = 0; j < 8; ++j)                  // cnt[j] is wave-uniform
            v_cnt = (lane == g * 8 + j) ? cnt[j] : v_cnt;
    }
    pcnt[c * NELEM + gid] = v_cnt;
}

// ---------------- Kernel 3: finalize rank + partial softmax denominator -----------
__global__ __launch_bounds__(256) void mod_finalize(const int* __restrict__ pcnt,
                                                    const float* __restrict__ scores,
                                                    int* __restrict__ rank_of,
                                                    float* __restrict__ partial) {
    const int gid = blockIdx.x * 256 + threadIdx.x;
    int r = 0;
#pragma unroll
    for (int c = 0; c < NCHUNK; ++c) r += pcnt[c * NELEM + gid];
    rank_of[gid] = r;

    float e = (r < KK) ? expf(scores[gid]) : 0.f;
    __shared__ float red[256];
    red[threadIdx.x] = e;
    __syncthreads();
    for (int off = 128; off > 0; off >>= 1) {
        if (threadIdx.x < off) red[threadIdx.x] += red[threadIdx.x + off];
        __syncthreads();
    }
    if (threadIdx.x == 0) partial[blockIdx.x] = red[0];
}

// ---------------- Kernel 4: blend/copy per token row, DESCENDING row order --------
// One row per block (r13 showed packing hurts); descending order (r12 best).
__global__ __launch_bounds__(256) void mod_blend(const float* __restrict__ x,
                                                 const float* __restrict__ proc,
                                                 const int* __restrict__ rank_of,
                                                 const float* __restrict__ scores,
                                                 const float* __restrict__ partial,
                                                 float* __restrict__ out) {
    const int row = (NELEM - 1) - blockIdx.x;   // descending: MRU x rows first
    const int b = row >> 12;
    const int t = threadIdx.x;
    const f32x4* xr = (const f32x4*)(x + (size_t)row * DD);
    f32x4* orow = (f32x4*)(out + (size_t)row * DD);
    const int j = rank_of[row];           // uniform per block -> scalar load
    f32x4 a = xr[t];
    if (j < KK) {
        float denom = 0.f;
#pragma unroll
        for (int i = 0; i < 16; ++i) denom += partial[b * 16 + i];  // deterministic
        float w = expf(scores[row]) / denom;
        const f32x4* pr = (const f32x4*)(proc + ((size_t)b * KK + j) * DD);
        f32x4 p = __builtin_nontemporal_load(pr + t);
        f32x4 o = p * w + (1.f - w) * a;
        __builtin_nontemporal_store(o, orow + t);
    } else {
        __builtin_nontemporal_store(a, orow + t);
    }
}

extern "C" void kernel_launch(void* const* d_in, const int* in_sizes, int n_in,
                              void* d_out, int out_size, void* d_ws, size_t ws_size,
                              hipStream_t stream) {
    const float* x    = (const float*)d_in[0];   // (B,S,D)
    const float* proc = (const float*)d_in[1];   // (B,K,D)
    const float* w    = (const float*)d_in[2];   // (D,)
    float* out = (float*)d_out;

    // workspace layout
    u64*   keys    = (u64*)d_ws;                                   // 256 KB
    float* scores  = (float*)((char*)d_ws + NELEM * 8);            // 128 KB
    int*   rank_of = (int*)((char*)d_ws + NELEM * 12);             // 128 KB
    int*   pcnt    = (int*)((char*)d_ws + NELEM * 16);             // 1 MB
    float* partial = (float*)((char*)d_ws + NELEM * 16 + NELEM * 4 * NCHUNK); // 512 B

    mod_scores      <<<NELEM / 4, 256, 0, stream>>>(x, w, scores, keys);
    mod_rank_partial<<<(NELEM / 256) * NCHUNK, 256, 0, stream>>>(keys, pcnt);
    mod_finalize    <<<NELEM / 256, 256, 0, stream>>>(pcnt, scores, rank_of, partial);
    mod_blend       <<<NELEM, 256, 0, stream>>>(x, proc, rank_of, scores, partial, out);
}